// Round 2
// baseline (121.993 us; speedup 1.0000x reference)
//
#include <hip/hip_runtime.h>

typedef short bf16x8 __attribute__((ext_vector_type(8)));
typedef float f32x4 __attribute__((ext_vector_type(4)));

#define MFMA16(a, b, c) __builtin_amdgcn_mfma_f32_16x16x32_bf16((a), (b), (c), 0, 0, 0)

#define GLOAD_LDS16(g, l)                                              \
  __builtin_amdgcn_global_load_lds(                                    \
      (const __attribute__((address_space(1))) unsigned int*)(g),      \
      (__attribute__((address_space(3))) unsigned int*)(l), 16, 0, 0)

__device__ __forceinline__ unsigned short f2b(float f) {
  union { float f; unsigned int u; } x; x.f = f;
  unsigned int r = x.u + 0x7FFFu + ((x.u >> 16) & 1u);
  return (unsigned short)(r >> 16);
}
__device__ __forceinline__ float b2f(unsigned short h) {
  union { unsigned int u; float f; } x; x.u = ((unsigned int)h) << 16;
  return x.f;
}

// ---------------- weight transpose+convert: W[512][512] f32 -> Wt[512n][512k] bf16
__global__ __launch_bounds__(256) void wtrans_kernel(
    const float* __restrict__ Wq, const float* __restrict__ Wk,
    const float* __restrict__ Wv, const float* __restrict__ Wo,
    short* __restrict__ Wt) {
  __shared__ float tile[64][65];
  const int z = blockIdx.z;
  const float* W = (z == 0) ? Wq : (z == 1) ? Wk : (z == 2) ? Wv : Wo;
  const int k0 = blockIdx.x * 64, n0 = blockIdx.y * 64;
  const int t = threadIdx.x;
  const int r = t >> 4, cc = (t & 15) * 4;
#pragma unroll
  for (int it = 0; it < 4; ++it) {
    int row = r + it * 16;
    const float4 v = *(const float4*)(W + (k0 + row) * 512 + n0 + cc);
    tile[row][cc + 0] = v.x; tile[row][cc + 1] = v.y;
    tile[row][cc + 2] = v.z; tile[row][cc + 3] = v.w;
  }
  __syncthreads();
  short* out = Wt + z * (512 * 512);
#pragma unroll
  for (int it = 0; it < 4; ++it) {
    int nrow = r + it * 16;
    unsigned int u0 = (unsigned int)f2b(tile[cc + 0][nrow]) | ((unsigned int)f2b(tile[cc + 1][nrow]) << 16);
    unsigned int u1 = (unsigned int)f2b(tile[cc + 2][nrow]) | ((unsigned int)f2b(tile[cc + 3][nrow]) << 16);
    uint2 uv; uv.x = u0; uv.y = u1;
    *(uint2*)(out + (n0 + nrow) * 512 + k0 + cc) = uv;
  }
}

// ---------------- convert Q,K f32 -> bf16
__global__ __launch_bounds__(256) void cvt_kernel(
    const float* __restrict__ Q, const float* __restrict__ K,
    short* __restrict__ Qb, short* __restrict__ Kb) {
  const float* src = blockIdx.y ? K : Q;
  short* dst = blockIdx.y ? Kb : Qb;
  int i = (blockIdx.x * 256 + threadIdx.x) * 8;
  float4 v0 = *(const float4*)(src + i);
  float4 v1 = *(const float4*)(src + i + 4);
  bf16x8 sv;
  sv[0] = (short)f2b(v0.x); sv[1] = (short)f2b(v0.y);
  sv[2] = (short)f2b(v0.z); sv[3] = (short)f2b(v0.w);
  sv[4] = (short)f2b(v1.x); sv[5] = (short)f2b(v1.y);
  sv[6] = (short)f2b(v1.z); sv[7] = (short)f2b(v1.w);
  *(bf16x8*)(dst + i) = sv;
}

// ---------------- m97-style GEMM mainloop: 128x128 tile, BK=64, gload_lds staging
// A bf16 [M][512], Wt bf16 [n][512] (pre-offset to tile's n-base). Linear LDS.
__device__ __forceinline__ void gemm_bf16_core(
    const short* __restrict__ A, const short* __restrict__ Wt,
    short* Al, short* Bl, int m0, int t, f32x4 acc[4][4]) {
  const int lane = t & 63, w = t >> 6;
  const int c = lane & 15, g = lane >> 4;
  const int wr = w >> 1, wc = w & 1;
  const int lr = lane >> 3, lc = (lane & 7) * 8;
  for (int kt = 0; kt < 8; ++kt) {
#pragma unroll
    for (int it = 0; it < 4; ++it) {
      int row = w * 32 + it * 8;
      GLOAD_LDS16(A + (size_t)(m0 + row + lr) * 512 + kt * 64 + lc, Al + row * 64);
      GLOAD_LDS16(Wt + (size_t)(row + lr) * 512 + kt * 64 + lc, Bl + row * 64);
    }
    __syncthreads();
#pragma unroll
    for (int kc = 0; kc < 2; ++kc) {
      bf16x8 af[4], bfr[4];
#pragma unroll
      for (int mi = 0; mi < 4; ++mi)
        af[mi] = *(const bf16x8*)(Al + (wr * 64 + mi * 16 + c) * 64 + kc * 32 + 8 * g);
#pragma unroll
      for (int ni = 0; ni < 4; ++ni)
        bfr[ni] = *(const bf16x8*)(Bl + (wc * 64 + ni * 16 + c) * 64 + kc * 32 + 8 * g);
#pragma unroll
      for (int mi = 0; mi < 4; ++mi)
#pragma unroll
        for (int ni = 0; ni < 4; ++ni)
          acc[mi][ni] = MFMA16(af[mi], bfr[ni], acc[mi][ni]);
    }
    __syncthreads();
  }
}

// ---------------- fused projections
// grid.y 0..3  : Qp  = (Qb@Wq + bq)*mask            n = y*128
// grid.y 4..7  : Kp  = (Kb@Wk + bk)*mask            n = (y-4)*128
// grid.y 8..11 : Vt  = (Kb@Wv + bv)*mask transposed d = (y-8)*128
__global__ __launch_bounds__(256) void proj2_kernel(
    const short* __restrict__ Qb, const short* __restrict__ Kb,
    const short* __restrict__ Wt4,
    const float* __restrict__ bq, const float* __restrict__ bk, const float* __restrict__ bv,
    const float* __restrict__ maskf,
    short* __restrict__ Qp, short* __restrict__ Kp, short* __restrict__ Vt) {
  __shared__ short Al[128 * 64];
  __shared__ short Bl[128 * 64];
  const int by = blockIdx.y;
  const int m0 = blockIdx.x * 128;
  const int t = threadIdx.x;
  const short* A;
  const short* Wt;
  const float* bias;
  int nbase;
  if (by < 4) { A = Qb; nbase = by * 128; Wt = Wt4 + nbase * 512; bias = bq; }
  else if (by < 8) { A = Kb; nbase = (by - 4) * 128; Wt = Wt4 + 262144 + nbase * 512; bias = bk; }
  else { A = Kb; nbase = (by - 8) * 128; Wt = Wt4 + 524288 + nbase * 512; bias = bv; }

  const f32x4 zz = {0.f, 0.f, 0.f, 0.f};
  f32x4 acc[4][4];
#pragma unroll
  for (int mi = 0; mi < 4; ++mi)
#pragma unroll
    for (int ni = 0; ni < 4; ++ni) acc[mi][ni] = zz;
  gemm_bf16_core(A, Wt, Al, Bl, m0, t, acc);

  const int lane = t & 63, w = t >> 6;
  const int c = lane & 15, g = lane >> 4;
  const int wr = w >> 1, wc = w & 1;
  float mk[4][4];
#pragma unroll
  for (int mi = 0; mi < 4; ++mi) {
    int mbase = m0 + wr * 64 + mi * 16 + 4 * g;
#pragma unroll
    for (int i = 0; i < 4; ++i) mk[mi][i] = maskf[mbase + i];
  }
  if (by < 8) {
    short* out = (by < 4) ? Qp : Kp;
#pragma unroll
    for (int ni = 0; ni < 4; ++ni) {
      int n = nbase + wc * 64 + ni * 16 + c;
      float bval = bias[n];
#pragma unroll
      for (int mi = 0; mi < 4; ++mi) {
        int mbase = m0 + wr * 64 + mi * 16 + 4 * g;
#pragma unroll
        for (int i = 0; i < 4; ++i)
          out[(size_t)(mbase + i) * 512 + n] = (short)f2b((acc[mi][ni][i] + bval) * mk[mi][i]);
      }
    }
  } else {
#pragma unroll
    for (int ni = 0; ni < 4; ++ni) {
      int d = nbase + wc * 64 + ni * 16 + c;
      int h = d >> 6, dd = d & 63;
      float bval = bias[d];
#pragma unroll
      for (int mi = 0; mi < 4; ++mi) {
        int mbase = m0 + wr * 64 + mi * 16 + 4 * g;
        int bi = mbase >> 10, seq0 = mbase & 1023;
        unsigned int u0 = (unsigned int)f2b((acc[mi][ni][0] + bval) * mk[mi][0]) |
                          ((unsigned int)f2b((acc[mi][ni][1] + bval) * mk[mi][1]) << 16);
        unsigned int u1 = (unsigned int)f2b((acc[mi][ni][2] + bval) * mk[mi][2]) |
                          ((unsigned int)f2b((acc[mi][ni][3] + bval) * mk[mi][3]) << 16);
        uint2 uv; uv.x = u0; uv.y = u1;
        *(uint2*)(Vt + ((size_t)(bi * 8 + h) * 64 + dd) * 1024 + seq0) = uv;
      }
    }
  }
}

// ---------------- flash attention per (h,b), QBLK=64 (wave=16 rows), KV tile 64
__global__ __launch_bounds__(256) void attn_kernel(
    const short* __restrict__ Qp, const short* __restrict__ Kp,
    const short* __restrict__ Vt, const float* __restrict__ mask,
    float* __restrict__ Ob, short* __restrict__ Obb) {
  __shared__ short Kl[64][72];
  __shared__ short Vl[64][72];
  __shared__ short Pl[4][16][72];
  const int t = threadIdx.x, lane = t & 63, w = t >> 6;
  const int c = lane & 15, g = lane >> 4;
  const int qt = blockIdx.x, hb = blockIdx.y;
  const int b = hb & 7, h = hb >> 3;
  const int n0 = qt * 64;
  const float scale = 0.04419417382415922f;  // 1/sqrt(512)

  bf16x8 qf0, qf1;
  {
    const short* qptr = Qp + ((b * 1024 + n0 + w * 16 + c) * 512 + h * 64 + 8 * g);
    qf0 = *(const bf16x8*)qptr;
    qf1 = *(const bf16x8*)(qptr + 32);
  }
  float runmax = -1e30f, lrun = 0.f;
  const f32x4 zz = {0.f, 0.f, 0.f, 0.f};
  f32x4 o[4];
  o[0] = zz; o[1] = zz; o[2] = zz; o[3] = zz;

  for (int kvt = 0; kvt < 16; ++kvt) {
#pragma unroll
    for (int it = 0; it < 2; ++it) {
      int idx = it * 256 + t;
      int row = idx >> 3, col8 = (idx & 7) << 3;
      *(bf16x8*)(&Kl[row][col8]) = *(const bf16x8*)(Kp + ((b * 1024 + kvt * 64 + row) * 512 + h * 64 + col8));
      *(bf16x8*)(&Vl[row][col8]) = *(const bf16x8*)(Vt + (((b * 8 + h) * 64 + row) * 1024 + kvt * 64 + col8));
    }
    __syncthreads();

    // S^T = K * q^T : lane holds P-row q=c, kv = 16j + 4g + i
    f32x4 s[4];
#pragma unroll
    for (int j = 0; j < 4; ++j) {
      f32x4 sj = zz;
      sj = MFMA16(*(const bf16x8*)(&Kl[16 * j + c][8 * g]), qf0, sj);
      sj = MFMA16(*(const bf16x8*)(&Kl[16 * j + c][32 + 8 * g]), qf1, sj);
      s[j] = sj;
    }

    float mt = -1e30f;
#pragma unroll
    for (int j = 0; j < 4; ++j)
      mt = fmaxf(mt, fmaxf(fmaxf(s[j][0], s[j][1]), fmaxf(s[j][2], s[j][3])));
    mt = fmaxf(mt, __shfl_xor(mt, 16));
    mt = fmaxf(mt, __shfl_xor(mt, 32));
    float newmax = fmaxf(runmax, mt);
    float factor = __expf(scale * (runmax - newmax));
    runmax = newmax;

    float tsum = 0.f;
#pragma unroll
    for (int j = 0; j < 4; ++j) {
      float4 m2 = *(const float4*)(mask + b * 1024 + kvt * 64 + 16 * j + 4 * g);
      float p0 = __expf(scale * (s[j][0] - runmax)) * m2.x;
      float p1 = __expf(scale * (s[j][1] - runmax)) * m2.y;
      float p2 = __expf(scale * (s[j][2] - runmax)) * m2.z;
      float p3 = __expf(scale * (s[j][3] - runmax)) * m2.w;
      tsum += (p0 + p1) + (p2 + p3);
      *(unsigned int*)(&Pl[w][c][16 * j + 4 * g]) = (unsigned int)f2b(p0) | ((unsigned int)f2b(p1) << 16);
      *(unsigned int*)(&Pl[w][c][16 * j + 4 * g + 2]) = (unsigned int)f2b(p2) | ((unsigned int)f2b(p3) << 16);
    }
    tsum += __shfl_xor(tsum, 16);
    tsum += __shfl_xor(tsum, 32);
    lrun = lrun * factor + tsum;

#pragma unroll
    for (int i = 0; i < 4; ++i) {
      float fi = __shfl(factor, 4 * g + i);
      o[0][i] *= fi; o[1][i] *= fi; o[2][i] *= fi; o[3][i] *= fi;
    }

#pragma unroll
    for (int ks = 0; ks < 2; ++ks) {
      bf16x8 pa = *(const bf16x8*)(&Pl[w][c][ks * 32 + 8 * g]);
#pragma unroll
      for (int nb = 0; nb < 4; ++nb) {
        bf16x8 vb = *(const bf16x8*)(&Vl[c + 16 * nb][ks * 32 + 8 * g]);
        o[nb] = MFMA16(pa, vb, o[nb]);
      }
    }
    __syncthreads();
  }

  float lr[4], mk1[4];
#pragma unroll
  for (int i = 0; i < 4; ++i) {
    lr[i] = __shfl(lrun, 4 * g + i);
    mk1[i] = mask[b * 1024 + n0 + w * 16 + 4 * g + i];
  }
#pragma unroll
  for (int nb = 0; nb < 4; ++nb) {
    int colg = h * 64 + 16 * nb + c;
#pragma unroll
    for (int i = 0; i < 4; ++i) {
      int row = n0 + w * 16 + 4 * g + i;
      float att = o[nb][i] / (lr[i] + 1e-16f);
      float qv = b2f(*(const unsigned short*)(Qp + (b * 1024 + row) * 512 + colg));
      float res = qv + mk1[i] * att;
      size_t off = (size_t)(b * 1024 + row) * 512 + colg;
      Ob[off] = res;
      Obb[off] = (short)f2b(res);
    }
  }
}

// ---------------- final: out = Ob + relu((Obb@Wo + bo) * mask)
__global__ __launch_bounds__(256) void final2_kernel(
    const short* __restrict__ Obb, const float* __restrict__ Obf,
    const short* __restrict__ Wto, const float* __restrict__ bo,
    const float* __restrict__ maskf, float* __restrict__ out) {
  __shared__ short Al[128 * 64];
  __shared__ short Bl[128 * 64];
  const int m0 = blockIdx.x * 128, n0 = blockIdx.y * 128;
  const int t = threadIdx.x;
  const f32x4 zz = {0.f, 0.f, 0.f, 0.f};
  f32x4 acc[4][4];
#pragma unroll
  for (int mi = 0; mi < 4; ++mi)
#pragma unroll
    for (int ni = 0; ni < 4; ++ni) acc[mi][ni] = zz;
  gemm_bf16_core(Obb, Wto + n0 * 512, Al, Bl, m0, t, acc);

  const int lane = t & 63, w = t >> 6;
  const int c = lane & 15, g = lane >> 4;
  const int wr = w >> 1, wc = w & 1;
  float mk[4][4];
#pragma unroll
  for (int mi = 0; mi < 4; ++mi) {
    int mbase = m0 + wr * 64 + mi * 16 + 4 * g;
#pragma unroll
    for (int i = 0; i < 4; ++i) mk[mi][i] = maskf[mbase + i];
  }
#pragma unroll
  for (int ni = 0; ni < 4; ++ni) {
    int n = n0 + wc * 64 + ni * 16 + c;
    float bval = bo[n];
#pragma unroll
    for (int mi = 0; mi < 4; ++mi) {
      int mbase = m0 + wr * 64 + mi * 16 + 4 * g;
#pragma unroll
      for (int i = 0; i < 4; ++i) {
        float v = (acc[mi][ni][i] + bval) * mk[mi][i];
        v = fmaxf(v, 0.f);
        size_t off = (size_t)(mbase + i) * 512 + n;
        out[off] = Obf[off] + v;
      }
    }
  }
}

extern "C" void kernel_launch(void* const* d_in, const int* in_sizes, int n_in,
                              void* d_out, int out_size, void* d_ws, size_t ws_size,
                              hipStream_t stream) {
  (void)in_sizes; (void)n_in; (void)out_size; (void)ws_size;
  const float* Q    = (const float*)d_in[0];
  const float* K    = (const float*)d_in[1];
  const float* mask = (const float*)d_in[2];
  const float* Wq   = (const float*)d_in[3];
  const float* bq   = (const float*)d_in[4];
  const float* Wk   = (const float*)d_in[5];
  const float* bk   = (const float*)d_in[6];
  const float* Wv   = (const float*)d_in[7];
  const float* bv   = (const float*)d_in[8];
  const float* Wo   = (const float*)d_in[9];
  const float* bo   = (const float*)d_in[10];

  char* ws = (char*)d_ws;
  const size_t MB = 1048576;
  short* Wt4 = (short*)ws;                 // 2 MiB: 4x 512x512 bf16 (Wq,Wk,Wv,Wo transposed)
  short* Qb  = (short*)(ws + 2 * MB);      // 8 MiB: Q bf16
  short* Kb  = (short*)(ws + 10 * MB);     // 8 MiB: K bf16
  short* Qp  = (short*)(ws + 18 * MB);     // 8 MiB
  short* Kp  = (short*)(ws + 26 * MB);     // 8 MiB
  short* Vt  = (short*)(ws + 34 * MB);     // 8 MiB: [B][H][64][1024]
  short* Obb = (short*)(ws + 42 * MB);     // 8 MiB: Obase bf16
  float* Ob  = (float*)(ws + 2 * MB);      // 16 MiB: Obase f32 (reuses Qb/Kb after proj)
  float* out = (float*)d_out;

  wtrans_kernel<<<dim3(8, 8, 4), 256, 0, stream>>>(Wq, Wk, Wv, Wo, Wt4);
  cvt_kernel<<<dim3(2048, 2), 256, 0, stream>>>(Q, K, Qb, Kb);
  proj2_kernel<<<dim3(64, 12), 256, 0, stream>>>(Qb, Kb, Wt4, bq, bk, bv, mask, Qp, Kp, Vt);
  attn_kernel<<<dim3(16, 64), 256, 0, stream>>>(Qp, Kp, Vt, mask, Ob, Obb);
  final2_kernel<<<dim3(64, 4), 256, 0, stream>>>(Obb, Ob, Wt4 + 3 * 262144, bo, mask, out);
}

// Round 3
// 117.959 us; speedup vs baseline: 1.0342x; 1.0342x over previous
//
#include <hip/hip_runtime.h>

typedef short bf16x8 __attribute__((ext_vector_type(8)));
typedef float f32x4 __attribute__((ext_vector_type(4)));

#define MFMA16(a, b, c) __builtin_amdgcn_mfma_f32_16x16x32_bf16((a), (b), (c), 0, 0, 0)

#define GLOAD_LDS16(g, l)                                              \
  __builtin_amdgcn_global_load_lds(                                    \
      (const __attribute__((address_space(1))) unsigned int*)(g),      \
      (__attribute__((address_space(3))) unsigned int*)(l), 16, 0, 0)

__device__ __forceinline__ unsigned short f2b(float f) {
  union { float f; unsigned int u; } x; x.f = f;
  unsigned int r = x.u + 0x7FFFu + ((x.u >> 16) & 1u);
  return (unsigned short)(r >> 16);
}
__device__ __forceinline__ float b2f(unsigned short h) {
  union { unsigned int u; float f; } x; x.u = ((unsigned int)h) << 16;
  return x.f;
}
__device__ __forceinline__ unsigned int cvtpk(float lo, float hi) {
  unsigned int r;
  asm("v_cvt_pk_bf16_f32 %0, %1, %2" : "=v"(r) : "v"(lo), "v"(hi));
  return r;
}

// ---------------- weight transpose+convert: W[512][512] f32 -> Wt[512n][512k] bf16
__global__ __launch_bounds__(256) void wtrans_kernel(
    const float* __restrict__ Wq, const float* __restrict__ Wk,
    const float* __restrict__ Wv, const float* __restrict__ Wo,
    short* __restrict__ Wt) {
  __shared__ float tile[64][65];
  const int z = blockIdx.z;
  const float* W = (z == 0) ? Wq : (z == 1) ? Wk : (z == 2) ? Wv : Wo;
  const int k0 = blockIdx.x * 64, n0 = blockIdx.y * 64;
  const int t = threadIdx.x;
  const int r = t >> 4, cc = (t & 15) * 4;
#pragma unroll
  for (int it = 0; it < 4; ++it) {
    int row = r + it * 16;
    const float4 v = *(const float4*)(W + (k0 + row) * 512 + n0 + cc);
    tile[row][cc + 0] = v.x; tile[row][cc + 1] = v.y;
    tile[row][cc + 2] = v.z; tile[row][cc + 3] = v.w;
  }
  __syncthreads();
  short* out = Wt + z * (512 * 512);
#pragma unroll
  for (int it = 0; it < 4; ++it) {
    int nrow = r + it * 16;
    unsigned int u0 = cvtpk(tile[cc + 0][nrow], tile[cc + 1][nrow]);
    unsigned int u1 = cvtpk(tile[cc + 2][nrow], tile[cc + 3][nrow]);
    uint2 uv; uv.x = u0; uv.y = u1;
    *(uint2*)(out + (n0 + nrow) * 512 + k0 + cc) = uv;
  }
}

// ---------------- convert Q,K f32 -> bf16
__global__ __launch_bounds__(256) void cvt_kernel(
    const float* __restrict__ Q, const float* __restrict__ K,
    short* __restrict__ Qb, short* __restrict__ Kb) {
  const float* src = blockIdx.y ? K : Q;
  short* dst = blockIdx.y ? Kb : Qb;
  int i = (blockIdx.x * 256 + threadIdx.x) * 8;
  float4 v0 = *(const float4*)(src + i);
  float4 v1 = *(const float4*)(src + i + 4);
  uint2 a, b;
  a.x = cvtpk(v0.x, v0.y); a.y = cvtpk(v0.z, v0.w);
  b.x = cvtpk(v1.x, v1.y); b.y = cvtpk(v1.z, v1.w);
  *(uint2*)(dst + i) = a;
  *(uint2*)(dst + i + 4) = b;
}

// ---------------- m97-style GEMM mainloop: 128x128 tile, BK=64, gload_lds staging
__device__ __forceinline__ void gemm_bf16_core(
    const short* __restrict__ A, const short* __restrict__ Wt,
    short* Al, short* Bl, int m0, int t, f32x4 acc[4][4]) {
  const int lane = t & 63, w = t >> 6;
  const int c = lane & 15, g = lane >> 4;
  const int wr = w >> 1, wc = w & 1;
  const int lr = lane >> 3, lc = (lane & 7) * 8;
  for (int kt = 0; kt < 8; ++kt) {
#pragma unroll
    for (int it = 0; it < 4; ++it) {
      int row = w * 32 + it * 8;
      GLOAD_LDS16(A + (size_t)(m0 + row + lr) * 512 + kt * 64 + lc, Al + row * 64);
      GLOAD_LDS16(Wt + (size_t)(row + lr) * 512 + kt * 64 + lc, Bl + row * 64);
    }
    __syncthreads();
#pragma unroll
    for (int kc = 0; kc < 2; ++kc) {
      bf16x8 af[4], bfr[4];
#pragma unroll
      for (int mi = 0; mi < 4; ++mi)
        af[mi] = *(const bf16x8*)(Al + (wr * 64 + mi * 16 + c) * 64 + kc * 32 + 8 * g);
#pragma unroll
      for (int ni = 0; ni < 4; ++ni)
        bfr[ni] = *(const bf16x8*)(Bl + (wc * 64 + ni * 16 + c) * 64 + kc * 32 + 8 * g);
#pragma unroll
      for (int mi = 0; mi < 4; ++mi)
#pragma unroll
        for (int ni = 0; ni < 4; ++ni)
          acc[mi][ni] = MFMA16(af[mi], bfr[ni], acc[mi][ni]);
    }
    __syncthreads();
  }
}

// ---------------- fused projections
__global__ __launch_bounds__(256) void proj2_kernel(
    const short* __restrict__ Qb, const short* __restrict__ Kb,
    const short* __restrict__ Wt4,
    const float* __restrict__ bq, const float* __restrict__ bk, const float* __restrict__ bv,
    const float* __restrict__ maskf,
    short* __restrict__ Qp, short* __restrict__ Kp, short* __restrict__ Vt) {
  __shared__ short Al[128 * 64];
  __shared__ short Bl[128 * 64];
  const int by = blockIdx.y;
  const int m0 = blockIdx.x * 128;
  const int t = threadIdx.x;
  const short* A;
  const short* Wt;
  const float* bias;
  int nbase;
  if (by < 4) { A = Qb; nbase = by * 128; Wt = Wt4 + nbase * 512; bias = bq; }
  else if (by < 8) { A = Kb; nbase = (by - 4) * 128; Wt = Wt4 + 262144 + nbase * 512; bias = bk; }
  else { A = Kb; nbase = (by - 8) * 128; Wt = Wt4 + 524288 + nbase * 512; bias = bv; }

  const f32x4 zz = {0.f, 0.f, 0.f, 0.f};
  f32x4 acc[4][4];
#pragma unroll
  for (int mi = 0; mi < 4; ++mi)
#pragma unroll
    for (int ni = 0; ni < 4; ++ni) acc[mi][ni] = zz;
  gemm_bf16_core(A, Wt, Al, Bl, m0, t, acc);

  const int lane = t & 63, w = t >> 6;
  const int c = lane & 15, g = lane >> 4;
  const int wr = w >> 1, wc = w & 1;
  float mk[4][4];
#pragma unroll
  for (int mi = 0; mi < 4; ++mi) {
    int mbase = m0 + wr * 64 + mi * 16 + 4 * g;
#pragma unroll
    for (int i = 0; i < 4; ++i) mk[mi][i] = maskf[mbase + i];
  }
  if (by < 8) {
    short* out = (by < 4) ? Qp : Kp;
#pragma unroll
    for (int ni = 0; ni < 4; ++ni) {
      int n = nbase + wc * 64 + ni * 16 + c;
      float bval = bias[n];
#pragma unroll
      for (int mi = 0; mi < 4; ++mi) {
        int mbase = m0 + wr * 64 + mi * 16 + 4 * g;
#pragma unroll
        for (int i = 0; i < 4; ++i)
          out[(size_t)(mbase + i) * 512 + n] = (short)f2b((acc[mi][ni][i] + bval) * mk[mi][i]);
      }
    }
  } else {
#pragma unroll
    for (int ni = 0; ni < 4; ++ni) {
      int d = nbase + wc * 64 + ni * 16 + c;
      int h = d >> 6, dd = d & 63;
      float bval = bias[d];
#pragma unroll
      for (int mi = 0; mi < 4; ++mi) {
        int mbase = m0 + wr * 64 + mi * 16 + 4 * g;
        int bi = mbase >> 10, seq0 = mbase & 1023;
        unsigned int u0 = cvtpk((acc[mi][ni][0] + bval) * mk[mi][0],
                                (acc[mi][ni][1] + bval) * mk[mi][1]);
        unsigned int u1 = cvtpk((acc[mi][ni][2] + bval) * mk[mi][2],
                                (acc[mi][ni][3] + bval) * mk[mi][3]);
        uint2 uv; uv.x = u0; uv.y = u1;
        *(uint2*)(Vt + ((size_t)(bi * 8 + h) * 64 + dd) * 1024 + seq0) = uv;
      }
    }
  }
}

// ---------------- flash attention per (h,b): async dbuf staging, XOR-swizzled LDS
__global__ __launch_bounds__(256) void attn_kernel(
    const short* __restrict__ Qp, const short* __restrict__ Kp,
    const short* __restrict__ Vt, const float* __restrict__ mask,
    float* __restrict__ Ob, short* __restrict__ Obb) {
  __shared__ short Kl[2][64][64];   // 16 KB, XOR-swizzled (slot ^ (row&7))
  __shared__ short Vl[2][64][64];   // 16 KB
  __shared__ short Pl[4][16][64];   //  8 KB, per-wave, swizzled
  const int t = threadIdx.x, lane = t & 63, w = t >> 6;
  const int c = lane & 15, g = lane >> 4;
  // XCD-aware swizzle: 16 consecutive logical blocks (one (b,h)) per XCD chunk
  const int hw = blockIdx.x;
  const int L = (hw & 7) * 128 + (hw >> 3);
  const int qt = L & 15, hb = L >> 4;
  const int b = hb & 7, h = hb >> 3;
  const int n0 = qt * 64;
  const float scale2 = 0.06375870724f;  // log2(e)/sqrt(512)
  const float DEFER = 125.0f;           // ~8/scale2

  // staging: lane covers row srow of an 8-row group, 16B slot (lane&7), pre-swizzled
  const int srow = lane >> 3;
  const int sswz = ((lane & 7) ^ srow) << 3;  // shorts
  const size_t kgbase = (size_t)(b * 1024) * 512 + h * 64;
  const size_t vgbase = (size_t)((b * 8 + h) * 64) * 1024;
  const int r0 = w * 16, r1 = w * 16 + 8;
  const int swc = (c & 7) << 3;  // read-side XOR key (shorts)

  bf16x8 qf0, qf1;
  {
    const short* qptr = Qp + ((size_t)(b * 1024 + n0 + w * 16 + c) * 512 + h * 64 + 8 * g);
    qf0 = *(const bf16x8*)qptr;
    qf1 = *(const bf16x8*)(qptr + 32);
  }

  // stage tile 0
  GLOAD_LDS16(Kp + kgbase + (size_t)(r0 + srow) * 512 + sswz, &Kl[0][r0][0]);
  GLOAD_LDS16(Kp + kgbase + (size_t)(r1 + srow) * 512 + sswz, &Kl[0][r1][0]);
  GLOAD_LDS16(Vt + vgbase + (size_t)(r0 + srow) * 1024 + sswz, &Vl[0][r0][0]);
  GLOAD_LDS16(Vt + vgbase + (size_t)(r1 + srow) * 1024 + sswz, &Vl[0][r1][0]);
  __syncthreads();

  float runmax = -1e30f, lrun = 0.f;
  const f32x4 zz = {0.f, 0.f, 0.f, 0.f};
  f32x4 o[4];
  o[0] = zz; o[1] = zz; o[2] = zz; o[3] = zz;

  for (int kvt = 0; kvt < 16; ++kvt) {
    const int cur = kvt & 1, nxt = cur ^ 1;

    // mask loads FIRST (so their vmcnt wait doesn't drain the prefetch below)
    float4 m2[4];
#pragma unroll
    for (int j = 0; j < 4; ++j)
      m2[j] = *(const float4*)(mask + b * 1024 + kvt * 64 + 16 * j + 4 * g);

    // async prefetch of next tile into the other buffer
    if (kvt < 15) {
      const int kr = (kvt + 1) * 64;
      GLOAD_LDS16(Kp + kgbase + (size_t)(kr + r0 + srow) * 512 + sswz, &Kl[nxt][r0][0]);
      GLOAD_LDS16(Kp + kgbase + (size_t)(kr + r1 + srow) * 512 + sswz, &Kl[nxt][r1][0]);
      GLOAD_LDS16(Vt + vgbase + (size_t)(r0 + srow) * 1024 + kr + sswz, &Vl[nxt][r0][0]);
      GLOAD_LDS16(Vt + vgbase + (size_t)(r1 + srow) * 1024 + kr + sswz, &Vl[nxt][r1][0]);
    }

    // QK^T swapped: lane holds S^T[kv block][q=c]
    f32x4 s[4];
#pragma unroll
    for (int j = 0; j < 4; ++j) {
      f32x4 sj = zz;
      sj = MFMA16(*(const bf16x8*)(&Kl[cur][16 * j + c][(8 * g) ^ swc]), qf0, sj);
      sj = MFMA16(*(const bf16x8*)(&Kl[cur][16 * j + c][(32 + 8 * g) ^ swc]), qf1, sj);
      s[j] = sj;
    }

    float mt = fmaxf(fmaxf(fmaxf(s[0][0], s[0][1]), fmaxf(s[0][2], s[0][3])),
                     fmaxf(fmaxf(s[1][0], s[1][1]), fmaxf(s[1][2], s[1][3])));
    mt = fmaxf(mt, fmaxf(fmaxf(fmaxf(s[2][0], s[2][1]), fmaxf(s[2][2], s[2][3])),
                         fmaxf(fmaxf(s[3][0], s[3][1]), fmaxf(s[3][2], s[3][3]))));
    mt = fmaxf(mt, __shfl_xor(mt, 16));
    mt = fmaxf(mt, __shfl_xor(mt, 32));

    // T13 defer-rescale: only rescale when the max moved materially
    if (!__all(mt <= runmax + DEFER)) {
      float newmax = fmaxf(runmax, mt);
      float factor = exp2f(scale2 * (runmax - newmax));
      runmax = newmax;
      lrun *= factor;
#pragma unroll
      for (int i = 0; i < 4; ++i) {
        float fi = __shfl(factor, 4 * g + i);
        o[0][i] *= fi; o[1][i] *= fi; o[2][i] *= fi; o[3][i] *= fi;
      }
    }

    const float negb = -scale2 * runmax;
    float tsum = 0.f;
#pragma unroll
    for (int j = 0; j < 4; ++j) {
      float p0 = exp2f(fmaf(scale2, s[j][0], negb)) * m2[j].x;
      float p1 = exp2f(fmaf(scale2, s[j][1], negb)) * m2[j].y;
      float p2 = exp2f(fmaf(scale2, s[j][2], negb)) * m2[j].z;
      float p3 = exp2f(fmaf(scale2, s[j][3], negb)) * m2[j].w;
      tsum += (p0 + p1) + (p2 + p3);
      uint2 pw; pw.x = cvtpk(p0, p1); pw.y = cvtpk(p2, p3);
      *(uint2*)(&Pl[w][c][(16 * j + 4 * g) ^ swc]) = pw;
    }
    tsum += __shfl_xor(tsum, 16);
    tsum += __shfl_xor(tsum, 32);
    lrun += tsum;

#pragma unroll
    for (int ks = 0; ks < 2; ++ks) {
      bf16x8 pa = *(const bf16x8*)(&Pl[w][c][(ks * 32 + 8 * g) ^ swc]);
#pragma unroll
      for (int nb = 0; nb < 4; ++nb) {
        bf16x8 vb = *(const bf16x8*)(&Vl[cur][16 * nb + c][(ks * 32 + 8 * g) ^ swc]);
        o[nb] = MFMA16(pa, vb, o[nb]);
      }
    }
    __syncthreads();  // drains prefetch vmcnt + joins waves; single barrier/tile
  }

  float lr[4], mk1[4];
#pragma unroll
  for (int i = 0; i < 4; ++i) {
    lr[i] = __shfl(lrun, 4 * g + i);
    mk1[i] = mask[b * 1024 + n0 + w * 16 + 4 * g + i];
  }
#pragma unroll
  for (int nb = 0; nb < 4; ++nb) {
    int colg = h * 64 + 16 * nb + c;
#pragma unroll
    for (int i = 0; i < 4; ++i) {
      int row = n0 + w * 16 + 4 * g + i;
      float att = o[nb][i] / (lr[i] + 1e-16f);
      float qv = b2f(*(const unsigned short*)(Qp + (size_t)(b * 1024 + row) * 512 + colg));
      float res = qv + mk1[i] * att;
      size_t off = (size_t)(b * 1024 + row) * 512 + colg;
      Ob[off] = res;
      Obb[off] = (short)f2b(res);
    }
  }
}

// ---------------- final: out = Ob + relu((Obb@Wo + bo) * mask)
__global__ __launch_bounds__(256) void final2_kernel(
    const short* __restrict__ Obb, const float* __restrict__ Obf,
    const short* __restrict__ Wto, const float* __restrict__ bo,
    const float* __restrict__ maskf, float* __restrict__ out) {
  __shared__ short Al[128 * 64];
  __shared__ short Bl[128 * 64];
  const int m0 = blockIdx.x * 128, n0 = blockIdx.y * 128;
  const int t = threadIdx.x;
  const f32x4 zz = {0.f, 0.f, 0.f, 0.f};
  f32x4 acc[4][4];
#pragma unroll
  for (int mi = 0; mi < 4; ++mi)
#pragma unroll
    for (int ni = 0; ni < 4; ++ni) acc[mi][ni] = zz;
  gemm_bf16_core(Obb, Wto + n0 * 512, Al, Bl, m0, t, acc);

  const int lane = t & 63, w = t >> 6;
  const int c = lane & 15, g = lane >> 4;
  const int wr = w >> 1, wc = w & 1;
  float mk[4][4];
#pragma unroll
  for (int mi = 0; mi < 4; ++mi) {
    int mbase = m0 + wr * 64 + mi * 16 + 4 * g;
#pragma unroll
    for (int i = 0; i < 4; ++i) mk[mi][i] = maskf[mbase + i];
  }
#pragma unroll
  for (int ni = 0; ni < 4; ++ni) {
    int n = n0 + wc * 64 + ni * 16 + c;
    float bval = bo[n];
#pragma unroll
    for (int mi = 0; mi < 4; ++mi) {
      int mbase = m0 + wr * 64 + mi * 16 + 4 * g;
#pragma unroll
      for (int i = 0; i < 4; ++i) {
        float v = (acc[mi][ni][i] + bval) * mk[mi][i];
        v = fmaxf(v, 0.f);
        size_t off = (size_t)(mbase + i) * 512 + n;
        out[off] = Obf[off] + v;
      }
    }
  }
}

extern "C" void kernel_launch(void* const* d_in, const int* in_sizes, int n_in,
                              void* d_out, int out_size, void* d_ws, size_t ws_size,
                              hipStream_t stream) {
  (void)in_sizes; (void)n_in; (void)out_size; (void)ws_size;
  const float* Q    = (const float*)d_in[0];
  const float* K    = (const float*)d_in[1];
  const float* mask = (const float*)d_in[2];
  const float* Wq   = (const float*)d_in[3];
  const float* bq   = (const float*)d_in[4];
  const float* Wk   = (const float*)d_in[5];
  const float* bk   = (const float*)d_in[6];
  const float* Wv   = (const float*)d_in[7];
  const float* bv   = (const float*)d_in[8];
  const float* Wo   = (const float*)d_in[9];
  const float* bo   = (const float*)d_in[10];

  char* ws = (char*)d_ws;
  const size_t MB = 1048576;
  short* Wt4 = (short*)ws;                 // 2 MiB: 4x 512x512 bf16
  short* Qb  = (short*)(ws + 2 * MB);      // 8 MiB
  short* Kb  = (short*)(ws + 10 * MB);     // 8 MiB
  short* Qp  = (short*)(ws + 18 * MB);     // 8 MiB
  short* Kp  = (short*)(ws + 26 * MB);     // 8 MiB
  short* Vt  = (short*)(ws + 34 * MB);     // 8 MiB: [B][H][64][1024]
  short* Obb = (short*)(ws + 42 * MB);     // 8 MiB
  float* Ob  = (float*)(ws + 2 * MB);      // 16 MiB (reuses Qb/Kb after proj)
  float* out = (float*)d_out;

  wtrans_kernel<<<dim3(8, 8, 4), 256, 0, stream>>>(Wq, Wk, Wv, Wo, Wt4);
  cvt_kernel<<<dim3(2048, 2), 256, 0, stream>>>(Q, K, Qb, Kb);
  proj2_kernel<<<dim3(64, 12), 256, 0, stream>>>(Qb, Kb, Wt4, bq, bk, bv, mask, Qp, Kp, Vt);
  attn_kernel<<<dim3(1024), 256, 0, stream>>>(Qp, Kp, Vt, mask, Ob, Obb);
  final2_kernel<<<dim3(64, 4), 256, 0, stream>>>(Obb, Ob, Wt4 + 3 * 262144, bo, mask, out);
}